// Round 12
// baseline (1100.778 us; speedup 1.0000x reference)
//
#include <hip/hip_runtime.h>

#define DIM   256
#define NVEC  8192
#define NCODE 8192
#define DEPTH 4

#define KBLK  8                  // coarse k-splits; 1024 codes per block
#define KC    (NCODE / KBLK)
#define KT    (KC / 128)         // 8 code-tiles of 128 per block
#define FCAP  8192               // = NVEC: flag list can never overflow
#define FKS   32                 // fallback k-slices (256 codes each)
#define FV    8                  // fallback vectors per chunk
#define KAPPA 0.018f

typedef short  b8 __attribute__((ext_vector_type(8)));   // 8 bf16 raw
typedef short  b4 __attribute__((ext_vector_type(4)));
typedef float  f4 __attribute__((ext_vector_type(4)));

static __device__ __forceinline__ unsigned short f2bf(float f) {
  unsigned u = __float_as_uint(f);
  return (unsigned short)((u + 0x7FFFu + ((u >> 16) & 1u)) >> 16);  // RNE
}

static __device__ __forceinline__ void gll16(const void* g, void* l) {
  __builtin_amdgcn_global_load_lds(
      (const __attribute__((address_space(1))) void*)g,
      (__attribute__((address_space(3))) void*)l, 16, 0, 0);
}

// ---------------------------------------------------------------------------
// prep_norms: all-depth row norms: true ||c||^2 and bf16 ||ĉ||^2.
// ---------------------------------------------------------------------------
__global__ __launch_bounds__(256) void prep_norms(const float* __restrict__ cb_all,
                                                  float* __restrict__ cc,
                                                  float* __restrict__ cchat) {
  int row  = blockIdx.x * 4 + (threadIdx.x >> 6);
  int lane = threadIdx.x & 63;
  float4 v = *(const float4*)&cb_all[(size_t)row * DIM + lane * 4];
  float st = 0.f, sh = 0.f;
  float vv[4] = {v.x, v.y, v.z, v.w};
  #pragma unroll
  for (int j = 0; j < 4; ++j) {
    float hf = __uint_as_float(((unsigned)f2bf(vv[j])) << 16);
    st += vv[j] * vv[j];
    sh += hf * hf;
  }
  #pragma unroll
  for (int off = 32; off > 0; off >>= 1) {
    st += __shfl_down(st, off, 64);
    sh += __shfl_down(sh, off, 64);
  }
  if (lane == 0) { cc[row] = st; cchat[row] = sh; }
}

// ---------------------------------------------------------------------------
// prep_depth: codebook depth -> bf16 row-major (cbh) + f32 transposed (cbT).
// ---------------------------------------------------------------------------
__global__ __launch_bounds__(256) void prep_depth(const float* __restrict__ cbd,
                                                  unsigned short* __restrict__ cbh,
                                                  float* __restrict__ cbT) {
  __shared__ float ts[64][68];
  const int kb = blockIdx.x >> 2, db = blockIdx.x & 3;
  const int k0 = kb * 64, d0 = db * 64;
  const int t  = threadIdx.x;
  const int r  = t >> 2;
  const int c4 = (t & 3) * 16;

  const float* src = cbd + (size_t)(k0 + r) * DIM + d0 + c4;
  float4 q[4];
  #pragma unroll
  for (int i = 0; i < 4; ++i) q[i] = *(const float4*)(src + i * 4);

  b8 h0, h1;
  #pragma unroll
  for (int j = 0; j < 4; ++j) { h0[j] = (short)f2bf(q[0][j]); h0[4 + j] = (short)f2bf(q[1][j]); }
  #pragma unroll
  for (int j = 0; j < 4; ++j) { h1[j] = (short)f2bf(q[2][j]); h1[4 + j] = (short)f2bf(q[3][j]); }
  *(b8*)&cbh[(size_t)(k0 + r) * DIM + d0 + c4]     = h0;
  *(b8*)&cbh[(size_t)(k0 + r) * DIM + d0 + c4 + 8] = h1;

  #pragma unroll
  for (int i = 0; i < 4; ++i)
    #pragma unroll
    for (int j = 0; j < 4; ++j)
      ts[c4 + i * 4 + j][r] = q[i][j];
  __syncthreads();

  const int dd = t >> 2, kk4 = (t & 3) * 16;
  float* dst = cbT + (size_t)(d0 + dd) * NCODE + k0 + kk4;
  #pragma unroll
  for (int q4 = 0; q4 < 4; ++q4)
    *(float4*)(dst + q4 * 4) = *(const float4*)&ts[dd][kk4 + q4 * 4];
}

// ---------------------------------------------------------------------------
// init: resid = x (f32, in d_out), rb = bf16(x), rsum0 = ||x||^2
// ---------------------------------------------------------------------------
__global__ __launch_bounds__(256) void init_kernel(const float* __restrict__ x,
                                                   float* __restrict__ resid,
                                                   unsigned short* __restrict__ rb,
                                                   float* __restrict__ rsum0) {
  int n    = blockIdx.x * 4 + (threadIdx.x >> 6);
  int lane = threadIdx.x & 63;
  float4 v = *(const float4*)&x[(size_t)n * DIM + lane * 4];
  *(float4*)&resid[(size_t)n * DIM + lane * 4] = v;
  b4 hv; hv[0] = (short)f2bf(v.x); hv[1] = (short)f2bf(v.y);
  hv[2] = (short)f2bf(v.z); hv[3] = (short)f2bf(v.w);
  *(b4*)&rb[(size_t)n * DIM + lane * 4] = hv;
  float s = v.x * v.x + v.y * v.y + v.z * v.z + v.w * v.w;
  #pragma unroll
  for (int off = 32; off > 0; off >>= 1) s += __shfl_down(s, off, 64);
  if (lane == 0) rsum0[n] = s;
}

// ---------------------------------------------------------------------------
// coarse: bf16 MFMA distance GEMM, counted-vmcnt 3-buffer B pipeline (R11
// skeleton) with 2x4 wave grid: wave tile 64 rows x 32 codes. A lives in
// registers (ar[dt][kk][mf], 4 frags/dt-kk, preloaded once — swizzle cancels
// on raw rb rows); each wave reads only 2 B frags per kk (B LDS reads halved
// vs 4x2 grid). cchat staged in LDS so fold reads use lgkmcnt.
// grid = 64 mblk x KBLK (512 = 2/CU); partials [kblk][n].
// ---------------------------------------------------------------------------
__global__ __launch_bounds__(512, 2) void coarse_kernel(
    const unsigned short* __restrict__ rb,
    const unsigned short* __restrict__ cbh,
    const float* __restrict__ cchat,
    float* __restrict__ pv1, int* __restrict__ pi1, float* __restrict__ pv2,
    int* __restrict__ fcount) {
  // LDS: B0 @0, B1 @16384, B2 @32768, cchat @49152 (4KB)
  __shared__ __align__(16) char lds[53248];

  const int tid  = threadIdx.x;
  const int w    = tid >> 6;
  const int l    = tid & 63;
  const int mw   = w >> 2, kw = w & 3;          // 2 x 4 wave grid
  const int mblk = blockIdx.x / KBLK;
  const int kblk = blockIdx.x % KBLK;
  const int m0   = mblk * 128;
  const int K0   = kblk * KC;

  if (blockIdx.x == 0 && tid == 0) *fcount = 0;   // replaces memsetAsync

  // B staging: 1024 chunks of 16B per stage, 2 per thread
  int boff[2], ldst[2];
  #pragma unroll
  for (int it = 0; it < 2; ++it) {
    int o = it * 512 + tid;
    int row = o >> 3, ssl = (o & 7) ^ (row & 7);
    boff[it] = (K0 + row) * 512 + ssl * 16;        // bytes into cbh (+kt*65536)
    ldst[it] = o * 16;
  }
  // B fragment ds_read byte offsets (nf in {0,1}, kk in {0,1} -> ^64)
  int offB[2][2];
  #pragma unroll
  for (int nf = 0; nf < 2; ++nf) {
    int row = kw * 32 + nf * 16 + (l & 15);
    int base = row * 128 + (((l >> 4) ^ (row & 7)) * 16);
    offB[nf][0] = base; offB[nf][1] = base ^ 64;
  }

  // ---- one-time A fragment preload: global -> registers (32 x b8) ----
  b8 ar[4][2][4];                       // [dt][kk][mf]
  {
    const char* ab = (const char*)rb +
        (size_t)(m0 + mw * 64 + (l & 15)) * 512 + (l >> 4) * 16;
    #pragma unroll
    for (int dt = 0; dt < 4; ++dt)
      #pragma unroll
      for (int kk = 0; kk < 2; ++kk)
        #pragma unroll
        for (int mf = 0; mf < 4; ++mf)
          ar[dt][kk][mf] =
              *(const b8*)(ab + mf * (16 * 512) + dt * 128 + kk * 64);
  }
  // ---- one-time cchat -> LDS (1024 floats, 4KB) ----
  if (tid < 256)
    gll16((const char*)cchat + (size_t)K0 * 4 + tid * 16,
          lds + 49152 + tid * 16);

  asm volatile("s_waitcnt vmcnt(0)");   // A + cchat landed; vmcnt clean
  __builtin_amdgcn_sched_barrier(0);

  // prime B pipeline: stages 0 and 1
  #pragma unroll
  for (int s = 0; s < 2; ++s)
    #pragma unroll
    for (int it = 0; it < 2; ++it)
      gll16((const char*)cbh + boff[it] + (s >> 2) * 65536 + (s & 3) * 128,
            lds + (s % 3) * 16384 + ldst[it]);

  const float* ccl = (const float*)(lds + 49152);
  const int kgb = K0 + kw * 32 + (l & 15);

  float tv1[16], tv2[16];
  int   ti1[16];
  #pragma unroll
  for (int s = 0; s < 16; ++s) { tv1[s] = 3.4e38f; tv2[s] = 3.4e38f; ti1[s] = 0; }

  f4 acc[4][2];

  #pragma unroll
  for (int p = 0; p < 32; ++p) {
    const int kt = p >> 2, dt = p & 3, cb_ = p % 3;
    // wait current stage's 2 loads (leaving next stage's 2 in flight)
    if (p == 31) { asm volatile("s_waitcnt vmcnt(0)"); }
    else         { asm volatile("s_waitcnt vmcnt(2)"); }
    __builtin_amdgcn_s_barrier();
    __builtin_amdgcn_sched_barrier(0);  // rule-#18 fence: nothing hoists above
    // issue stage p+2 into buf[(p+2)%3] (read-free since stage p-1's barrier)
    if (p < 30) {
      const int s2 = p + 2, nb = s2 % 3, nkt = s2 >> 2, ndt = s2 & 3;
      #pragma unroll
      for (int it = 0; it < 2; ++it)
        gll16((const char*)cbh + boff[it] + nkt * 65536 + ndt * 128,
              lds + nb * 16384 + ldst[it]);
    }
    if (dt == 0) {
      #pragma unroll
      for (int i = 0; i < 4; ++i)
        #pragma unroll
        for (int j = 0; j < 2; ++j)
          acc[i][j] = (f4){0.f, 0.f, 0.f, 0.f};
    }
    __builtin_amdgcn_s_setprio(1);
    #pragma unroll
    for (int kk = 0; kk < 2; ++kk) {
      b8 bb[2];
      #pragma unroll
      for (int nf = 0; nf < 2; ++nf)
        bb[nf] = *(const b8*)(lds + cb_ * 16384 + offB[nf][kk]);
      #pragma unroll
      for (int mf = 0; mf < 4; ++mf)
        #pragma unroll
        for (int nf = 0; nf < 2; ++nf)
          acc[mf][nf] = __builtin_amdgcn_mfma_f32_16x16x32_bf16(
              ar[dt][kk][mf], bb[nf], acc[mf][nf], 0, 0, 0);
    }
    __builtin_amdgcn_s_setprio(0);
    if (dt == 3) {                      // fold tile kt into running top-2
      float cn[2]; int kg[2];
      #pragma unroll
      for (int nf = 0; nf < 2; ++nf) {
        kg[nf] = kgb + kt * 128 + nf * 16;
        cn[nf] = ccl[kt * 128 + kw * 32 + nf * 16 + (l & 15)];  // LDS: lgkmcnt
      }
      #pragma unroll
      for (int mf = 0; mf < 4; ++mf)
        #pragma unroll
        for (int r = 0; r < 4; ++r) {
          const int s0 = mf * 4 + r;
          #pragma unroll
          for (int nf = 0; nf < 2; ++nf) {
            float s = fmaf(-2.f, acc[mf][nf][r], cn[nf]);
            bool  c = s < tv1[s0];
            float m2 = fminf(tv2[s0], s);
            tv2[s0] = c ? tv1[s0] : m2;
            ti1[s0] = c ? kg[nf] : ti1[s0];
            tv1[s0] = c ? s : tv1[s0];
          }
        }
    }
  }
  __syncthreads();                      // full drain before LDS re-use

  // ---- single end-of-block reduction (alias lds as merge buffer) ----
  float* Mv1 = (float*)lds;             // [128][4]
  int*   Mi1 = (int*)(lds + 2048);
  float* Mv2 = (float*)(lds + 4096);

  #pragma unroll
  for (int s0 = 0; s0 < 16; ++s0) {
    float v1 = tv1[s0], v2 = tv2[s0];
    int   i1 = ti1[s0];
    #pragma unroll
    for (int m = 1; m < 16; m <<= 1) {     // butterfly over l&15 group
      float qv1 = __shfl_xor(v1, m);
      int   qi1 = __shfl_xor(i1, m);
      float qv2 = __shfl_xor(v2, m);
      bool  qw  = (qv1 < v1) || (qv1 == v1 && qi1 < i1);
      float lose = qw ? v1 : qv1;
      float wv2  = qw ? qv2 : v2;
      v2 = fminf(wv2, lose);
      if (qw) { v1 = qv1; i1 = qi1; }
    }
    if ((l & 15) == 0) {
      int mf = s0 >> 2, r = s0 & 3;
      int rowL = mw * 64 + mf * 16 + (l >> 4) * 4 + r;
      Mv1[rowL * 4 + kw] = v1; Mi1[rowL * 4 + kw] = i1; Mv2[rowL * 4 + kw] = v2;
    }
  }
  __syncthreads();
  if (tid < 128) {
    float v1 = Mv1[tid * 4], v2 = Mv2[tid * 4];
    int   i1 = Mi1[tid * 4];
    #pragma unroll
    for (int q = 1; q < 4; ++q) {
      float b1 = Mv1[tid * 4 + q], b2 = Mv2[tid * 4 + q];
      int   b1i = Mi1[tid * 4 + q];
      bool  bw = (b1 < v1) || (b1 == v1 && b1i < i1);
      float lose = bw ? v1 : b1;
      v2 = fminf(fminf(v2, b2), lose);
      if (bw) { v1 = b1; i1 = b1i; }
    }
    int n = m0 + tid;
    pv1[kblk * NVEC + n] = v1;
    pi1[kblk * NVEC + n] = i1;
    pv2[kblk * NVEC + n] = v2;
  }
}

// ---------------------------------------------------------------------------
// merge: global top2 over KBLK partials; provisional idx; flag near-ties.
// ---------------------------------------------------------------------------
__global__ __launch_bounds__(256) void merge_kernel(
    const float* __restrict__ pv1, const int* __restrict__ pi1,
    const float* __restrict__ pv2, const float* __restrict__ vnorm,
    int* __restrict__ idx, int* __restrict__ flist, int* __restrict__ fslot,
    int* __restrict__ fcount) {
  int n = blockIdx.x * 256 + threadIdx.x;
  float v1 = 3.4e38f, v2 = 3.4e38f; int i1 = 0;
  #pragma unroll
  for (int kb = 0; kb < KBLK; ++kb) {
    float b1 = pv1[kb * NVEC + n]; int b1i = pi1[kb * NVEC + n];
    float b2 = pv2[kb * NVEC + n];
    bool  bw = (b1 < v1) || (b1 == v1 && b1i < i1);
    float lose = bw ? v1 : b1;
    float wv2  = bw ? b2 : v2;
    v2 = fminf(wv2, lose);
    if (bw) { v1 = b1; i1 = b1i; }
  }
  idx[n] = i1;
  float thr = KAPPA * sqrtf(fmaxf(v1 + vnorm[n], 0.f)) + 1e-5f;
  int slot = -1;
  if (v2 - v1 < thr) {
    slot = atomicAdd(fcount, 1);
    flist[slot] = n;
  }
  fslot[n] = slot;
}

// ---------------------------------------------------------------------------
// fb_scan_t: exact f32 rescan for flagged vectors, transposed codebook.
// chunk = FV(8) vectors; grid = 256 chunk-slots x FKS = 8192 blocks.
// ---------------------------------------------------------------------------
__global__ __launch_bounds__(256, 4) void fb_scan_t(
    const float* __restrict__ cbT, const float* __restrict__ cc,
    const float* __restrict__ resid, const int* __restrict__ flist,
    const int* __restrict__ fcount,
    float* __restrict__ fpv, int* __restrict__ fpi) {
  __shared__ float vsT[DIM][FV + 4];       // 48B rows, f4-aligned
  __shared__ float mv[FV][4];
  __shared__ int   mi[FV][4];
  const int cnt = min(*fcount, FCAP);
  const int ks = blockIdx.x & (FKS - 1);
  const int t = threadIdx.x;
  const int w = t >> 6, l = t & 63;
  const int k = ks * 256 + t;
  const float cn = cc[k];

  for (int chunk = blockIdx.x >> 5; chunk * FV < cnt; chunk += 256) {
    __syncthreads();
    #pragma unroll
    for (int v = 0; v < FV; ++v) {
      int s = chunk * FV + v;
      int n = flist[s < cnt ? s : chunk * FV];
      vsT[t][v] = resid[(size_t)n * DIM + t];
    }
    __syncthreads();

    float dot[FV];
    #pragma unroll
    for (int v = 0; v < FV; ++v) dot[v] = 0.f;

    #pragma unroll 8
    for (int d = 0; d < DIM; ++d) {
      float cv = cbT[(size_t)d * NCODE + k];
      f4 a0 = *(const f4*)&vsT[d][0];
      f4 a1 = *(const f4*)&vsT[d][4];
      dot[0] = fmaf(cv, a0[0], dot[0]);
      dot[1] = fmaf(cv, a0[1], dot[1]);
      dot[2] = fmaf(cv, a0[2], dot[2]);
      dot[3] = fmaf(cv, a0[3], dot[3]);
      dot[4] = fmaf(cv, a1[0], dot[4]);
      dot[5] = fmaf(cv, a1[1], dot[5]);
      dot[6] = fmaf(cv, a1[2], dot[6]);
      dot[7] = fmaf(cv, a1[3], dot[7]);
    }

    #pragma unroll
    for (int v = 0; v < FV; ++v) {
      float bv = fmaf(-2.f, dot[v], cn);
      int   bi = k;
      #pragma unroll
      for (int m = 1; m < 64; m <<= 1) {
        float qv = __shfl_xor(bv, m);
        int   qi = __shfl_xor(bi, m);
        if (qv < bv || (qv == bv && qi < bi)) { bv = qv; bi = qi; }
      }
      if (l == 0) { mv[v][w] = bv; mi[v][w] = bi; }
    }
    __syncthreads();
    if (t < FV) {
      float bv = mv[t][0]; int bi = mi[t][0];
      #pragma unroll
      for (int ww = 1; ww < 4; ++ww) {
        float qv = mv[t][ww]; int qi = mi[t][ww];
        if (qv < bv || (qv == bv && qi < bi)) { bv = qv; bi = qi; }
      }
      if (chunk * FV + t < cnt) {
        fpv[(size_t)(chunk * FV + t) * FKS + ks] = bv;
        fpi[(size_t)(chunk * FV + t) * FKS + ks] = bi;
      }
    }
  }
}

// ---------------------------------------------------------------------------
// update: final idx (inline fb-merge for flagged); resid -= cb[idx];
// rb = bf16(resid); rsum; code out as float. One wave per vector.
// ---------------------------------------------------------------------------
__global__ __launch_bounds__(256) void update_kernel(
    const float* __restrict__ cb, const int* __restrict__ idx,
    const int* __restrict__ fslot,
    const float* __restrict__ fpv, const int* __restrict__ fpi,
    float* __restrict__ resid, unsigned short* __restrict__ rb,
    float* __restrict__ rsum_out, float* __restrict__ codes_out, int depth) {
  int n    = blockIdx.x * 4 + (threadIdx.x >> 6);
  int lane = threadIdx.x & 63;
  int s    = fslot[n];                   // wave-uniform
  int bi;
  if (s >= 0) {
    float v = 3.4e38f; int ii = 0x7fffffff;
    if (lane < FKS) { v = fpv[(size_t)s * FKS + lane]; ii = fpi[(size_t)s * FKS + lane]; }
    #pragma unroll
    for (int m = 1; m < FKS; m <<= 1) {
      float qv = __shfl_xor(v, m);
      int   qi = __shfl_xor(ii, m);
      if (qv < v || (qv == v && qi < ii)) { v = qv; ii = qi; }
    }
    bi = __shfl(ii, 0, 64);
  } else {
    bi = idx[n];
  }
  float4 q = *(const float4*)&cb[(size_t)bi * DIM + lane * 4];
  float4 r = *(float4*)&resid[(size_t)n * DIM + lane * 4];
  r.x -= q.x; r.y -= q.y; r.z -= q.z; r.w -= q.w;
  *(float4*)&resid[(size_t)n * DIM + lane * 4] = r;
  b4 hv; hv[0] = (short)f2bf(r.x); hv[1] = (short)f2bf(r.y);
  hv[2] = (short)f2bf(r.z); hv[3] = (short)f2bf(r.w);
  *(b4*)&rb[(size_t)n * DIM + lane * 4] = hv;
  float s2 = r.x * r.x + r.y * r.y + r.z * r.z + r.w * r.w;
  #pragma unroll
  for (int off = 32; off > 0; off >>= 1) s2 += __shfl_down(s2, off, 64);
  if (lane == 0) {
    rsum_out[n] = s2;
    codes_out[n * DEPTH + depth] = (float)bi;
  }
}

// ---------------------------------------------------------------------------
// finalize: quants = x - resid (in place); block 0 reduces commitment loss.
// ---------------------------------------------------------------------------
__global__ __launch_bounds__(256) void finalize(const float* __restrict__ x,
                                                float* __restrict__ out,
                                                const float* __restrict__ rsumL) {
  int i = blockIdx.x * blockDim.x + threadIdx.x;
  float4 r  = *(float4*)&out[(size_t)i * 4];
  float4 xv = *(const float4*)&x[(size_t)i * 4];
  float4 o;
  o.x = xv.x - r.x; o.y = xv.y - r.y; o.z = xv.z - r.z; o.w = xv.w - r.w;
  *(float4*)&out[(size_t)i * 4] = o;

  if (blockIdx.x == 0) {
    __shared__ float sm[256];
    float s = 0.f;
    for (int j = threadIdx.x; j < DEPTH * NVEC; j += 256) s += rsumL[j];
    sm[threadIdx.x] = s;
    __syncthreads();
    for (int off = 128; off > 0; off >>= 1) {
      if (threadIdx.x < off) sm[threadIdx.x] += sm[threadIdx.x + off];
      __syncthreads();
    }
    if (threadIdx.x == 0)
      out[NVEC * DIM] = sm[0] / (float)DEPTH / (float)(NVEC * DIM);
  }
}

// ---------------------------------------------------------------------------
extern "C" void kernel_launch(void* const* d_in, const int* in_sizes, int n_in,
                              void* d_out, int out_size, void* d_ws, size_t ws_size,
                              hipStream_t stream) {
  const float* x  = (const float*)d_in[0];
  const float* cb = (const float*)d_in[1];
  float* out = (float*)d_out;
  char*  wsb = (char*)d_ws;

  // ws layout (~20 MB, under the proven 22.3 MB)
  unsigned short* cbh = (unsigned short*)(wsb);                 // 4 MB (per-depth)
  unsigned short* rb  = (unsigned short*)(wsb + 4194304);       // 4 MB
  float* cbT   = (float*)(wsb + 8388608);                       // 8 MB (per-depth)
  float* cc    = (float*)(wsb + 16777216);                      // 128 KB
  float* cchat = (float*)(wsb + 16908288);                      // 128 KB
  float* pv1   = (float*)(wsb + 17039360);                      // 512 KB
  int*   pi1   = (int*)  (wsb + 17563648);                      // 512 KB
  float* pv2   = (float*)(wsb + 18087936);                      // 512 KB
  float* rsum  = (float*)(wsb + 18612224);                      // 160 KB
  int*   idx   = (int*)  (wsb + 18776064);                      // 32 KB
  int*   flist = (int*)  (wsb + 18808832);                      // 32 KB
  int*   fslot = (int*)  (wsb + 18841600);                      // 32 KB
  int*   fcount= (int*)  (wsb + 18874368);                      // 4 KB pad
  float* fpv   = (float*)(wsb + 18878464);                      // 1 MB
  int*   fpi   = (int*)  (wsb + 19927040);                      // 1 MB

  float* resid     = out;                    // quants region doubles as resid
  float* codes_out = out + NVEC * DIM + 1;

  prep_norms<<<(DEPTH * NCODE) / 4, 256, 0, stream>>>(cb, cc, cchat);
  init_kernel<<<NVEC / 4, 256, 0, stream>>>(x, resid, rb, rsum);

  for (int d = 0; d < DEPTH; ++d) {
    const size_t cbo = (size_t)d * NCODE * DIM;
    prep_depth<<<512, 256, 0, stream>>>(cb + cbo, cbh, cbT);
    coarse_kernel<<<(NVEC / 128) * KBLK, 512, 0, stream>>>(
        rb, cbh, cchat + d * NCODE, pv1, pi1, pv2, fcount);
    merge_kernel<<<NVEC / 256, 256, 0, stream>>>(
        pv1, pi1, pv2, rsum + d * NVEC, idx, flist, fslot, fcount);
    fb_scan_t<<<256 * FKS, 256, 0, stream>>>(
        cbT, cc + d * NCODE, resid, flist, fcount, fpv, fpi);
    update_kernel<<<NVEC / 4, 256, 0, stream>>>(
        cb + cbo, idx, fslot, fpv, fpi, resid, rb,
        rsum + (d + 1) * NVEC, codes_out, d);
  }
  finalize<<<(NVEC * DIM / 4) / 256, 256, 0, stream>>>(x, out, rsum + NVEC);
}

// Round 13
// 467.812 us; speedup vs baseline: 2.3530x; 2.3530x over previous
//
#include <hip/hip_runtime.h>

#define DIM   256
#define NVEC  8192
#define NCODE 8192
#define DEPTH 4

#define KBLK  8                  // coarse k-splits; 1024 codes per block
#define KC    (NCODE / KBLK)
#define KT    (KC / 128)         // 8 code-tiles of 128 per block
#define FCAP  8192               // = NVEC: flag list can never overflow
#define FKS   32                 // fallback k-slices (256 codes each)
#define FV    8                  // fallback vectors per chunk
#define KAPPA 0.018f

typedef short  b8 __attribute__((ext_vector_type(8)));   // 8 bf16 raw
typedef short  b4 __attribute__((ext_vector_type(4)));
typedef float  f4 __attribute__((ext_vector_type(4)));

static __device__ __forceinline__ unsigned short f2bf(float f) {
  unsigned u = __float_as_uint(f);
  return (unsigned short)((u + 0x7FFFu + ((u >> 16) & 1u)) >> 16);  // RNE
}

static __device__ __forceinline__ void gll16(const void* g, void* l) {
  __builtin_amdgcn_global_load_lds(
      (const __attribute__((address_space(1))) void*)g,
      (__attribute__((address_space(3))) void*)l, 16, 0, 0);
}

// ---------------------------------------------------------------------------
// prep_norms: all-depth row norms: true ||c||^2 and bf16 ||ĉ||^2.
// ---------------------------------------------------------------------------
__global__ __launch_bounds__(256) void prep_norms(const float* __restrict__ cb_all,
                                                  float* __restrict__ cc,
                                                  float* __restrict__ cchat) {
  int row  = blockIdx.x * 4 + (threadIdx.x >> 6);
  int lane = threadIdx.x & 63;
  float4 v = *(const float4*)&cb_all[(size_t)row * DIM + lane * 4];
  float st = 0.f, sh = 0.f;
  float vv[4] = {v.x, v.y, v.z, v.w};
  #pragma unroll
  for (int j = 0; j < 4; ++j) {
    float hf = __uint_as_float(((unsigned)f2bf(vv[j])) << 16);
    st += vv[j] * vv[j];
    sh += hf * hf;
  }
  #pragma unroll
  for (int off = 32; off > 0; off >>= 1) {
    st += __shfl_down(st, off, 64);
    sh += __shfl_down(sh, off, 64);
  }
  if (lane == 0) { cc[row] = st; cchat[row] = sh; }
}

// ---------------------------------------------------------------------------
// prep_depth: codebook depth -> bf16 row-major (cbh) + f32 transposed (cbT).
// ---------------------------------------------------------------------------
__global__ __launch_bounds__(256) void prep_depth(const float* __restrict__ cbd,
                                                  unsigned short* __restrict__ cbh,
                                                  float* __restrict__ cbT) {
  __shared__ float ts[64][68];
  const int kb = blockIdx.x >> 2, db = blockIdx.x & 3;
  const int k0 = kb * 64, d0 = db * 64;
  const int t  = threadIdx.x;
  const int r  = t >> 2;
  const int c4 = (t & 3) * 16;

  const float* src = cbd + (size_t)(k0 + r) * DIM + d0 + c4;
  float4 q[4];
  #pragma unroll
  for (int i = 0; i < 4; ++i) q[i] = *(const float4*)(src + i * 4);

  b8 h0, h1;
  #pragma unroll
  for (int j = 0; j < 4; ++j) { h0[j] = (short)f2bf(q[0][j]); h0[4 + j] = (short)f2bf(q[1][j]); }
  #pragma unroll
  for (int j = 0; j < 4; ++j) { h1[j] = (short)f2bf(q[2][j]); h1[4 + j] = (short)f2bf(q[3][j]); }
  *(b8*)&cbh[(size_t)(k0 + r) * DIM + d0 + c4]     = h0;
  *(b8*)&cbh[(size_t)(k0 + r) * DIM + d0 + c4 + 8] = h1;

  #pragma unroll
  for (int i = 0; i < 4; ++i)
    #pragma unroll
    for (int j = 0; j < 4; ++j)
      ts[c4 + i * 4 + j][r] = q[i][j];
  __syncthreads();

  const int dd = t >> 2, kk4 = (t & 3) * 16;
  float* dst = cbT + (size_t)(d0 + dd) * NCODE + k0 + kk4;
  #pragma unroll
  for (int q4 = 0; q4 < 4; ++q4)
    *(float4*)(dst + q4 * 4) = *(const float4*)&ts[dd][kk4 + q4 * 4];
}

// ---------------------------------------------------------------------------
// init: resid = x (f32, in d_out), rb = bf16(x), rsum0 = ||x||^2
// ---------------------------------------------------------------------------
__global__ __launch_bounds__(256) void init_kernel(const float* __restrict__ x,
                                                   float* __restrict__ resid,
                                                   unsigned short* __restrict__ rb,
                                                   float* __restrict__ rsum0) {
  int n    = blockIdx.x * 4 + (threadIdx.x >> 6);
  int lane = threadIdx.x & 63;
  float4 v = *(const float4*)&x[(size_t)n * DIM + lane * 4];
  *(float4*)&resid[(size_t)n * DIM + lane * 4] = v;
  b4 hv; hv[0] = (short)f2bf(v.x); hv[1] = (short)f2bf(v.y);
  hv[2] = (short)f2bf(v.z); hv[3] = (short)f2bf(v.w);
  *(b4*)&rb[(size_t)n * DIM + lane * 4] = hv;
  float s = v.x * v.x + v.y * v.y + v.z * v.z + v.w * v.w;
  #pragma unroll
  for (int off = 32; off > 0; off >>= 1) s += __shfl_down(s, off, 64);
  if (lane == 0) rsum0[n] = s;
}

// ---------------------------------------------------------------------------
// coarse: bf16 MFMA distance GEMM, double-buffered 2-phase pipeline (R10
// verbatim — best measured: 58us, VGPR 84, no spill). A-register cache:
// the A tile is identical for all KT code-tiles, so A is staged+ds_read
// only during kt==0 and kept in 16 b8 registers (ar[dt][kk][mf], all
// compile-time indices). kt>=1 stages issue only B staging + B ds_reads.
// launch_bounds (512,2): 256-VGPR cap — (512,4)'s 128 cap spills ar (R9).
// 512 threads = 8 waves as 4x2 (mw,kw); wave tile 32x128.
// grid = 64 mblk x KBLK (512 = exactly 2/CU); partials [kblk][n].
// ---------------------------------------------------------------------------
__global__ __launch_bounds__(512, 2) void coarse_kernel(
    const unsigned short* __restrict__ rb,
    const unsigned short* __restrict__ cbh,
    const float* __restrict__ cchat,
    float* __restrict__ pv1, int* __restrict__ pi1, float* __restrict__ pv2,
    int* __restrict__ fcount) {
  // layout: A0 @0, B0 @16384, A1 @32768, B1 @49152
  __shared__ __align__(16) char lds[65536];

  const int tid  = threadIdx.x;
  const int w    = tid >> 6;
  const int l    = tid & 63;
  const int mw   = w >> 1, kw = w & 1;          // 4 x 2 wave grid
  const int mblk = blockIdx.x / KBLK;
  const int kblk = blockIdx.x % KBLK;
  const int m0   = mblk * 128;
  const int K0   = kblk * KC;

  if (blockIdx.x == 0 && tid == 0) *fcount = 0;   // replaces memsetAsync

  // staging offsets: 1024 chunks of 16B per tile, 2 per thread
  int aoff[2], boff[2], ldst[2];
  #pragma unroll
  for (int it = 0; it < 2; ++it) {
    int o = it * 512 + tid;
    int row = o >> 3, ssl = (o & 7) ^ (row & 7);
    aoff[it] = (m0 + row) * 512 + ssl * 16;        // bytes into rb
    boff[it] = (K0 + row) * 512 + ssl * 16;        // bytes into cbh (+kt*65536)
    ldst[it] = o * 16;
  }
  // fragment ds_read byte offsets (kk in {0,1} -> ^64)
  int offA[2][2], offB[4][2];
  #pragma unroll
  for (int mf = 0; mf < 2; ++mf) {
    int row = mw * 32 + mf * 16 + (l & 15);
    int base = row * 128 + (((l >> 4) ^ (row & 7)) * 16);
    offA[mf][0] = base; offA[mf][1] = base ^ 64;
  }
  #pragma unroll
  for (int nf = 0; nf < 4; ++nf) {
    int row = kw * 64 + nf * 16 + (l & 15);
    int base = row * 128 + (((l >> 4) ^ (row & 7)) * 16);
    offB[nf][0] = base; offB[nf][1] = base ^ 64;
  }

  const int kgb = K0 + kw * 64 + (l & 15);

  float tv1[8], tv2[8];
  int   ti1[8];
  #pragma unroll
  for (int s = 0; s < 8; ++s) { tv1[s] = 3.4e38f; tv2[s] = 3.4e38f; ti1[s] = 0; }

  f4 acc[2][4];
  b8 ar[4][2][2];                       // A cache [dt][kk][mf], 64 VGPR

  // prologue: stage (kt0, dt0) A+B into buf 0
  #pragma unroll
  for (int it = 0; it < 2; ++it) {
    gll16((const char*)rb  + aoff[it], lds + ldst[it]);
    gll16((const char*)cbh + boff[it], lds + 16384 + ldst[it]);
  }
  __syncthreads();

  for (int kt = 0; kt < KT; ++kt) {
    #pragma unroll
    for (int dt = 0; dt < 4; ++dt) {
      const int buf = dt & 1;           // compile-time
      // prefetch next stage into the alternate buffer
      if (!(kt == KT - 1 && dt == 3)) {
        const int ndt = (dt + 1) & 3;   // compile-time
        const int nb  = ndt & 1;
        const int nktoff = (dt == 3) ? (kt + 1) * 65536 : kt * 65536;
        if (kt == 0 && dt < 3) {        // A needed only for kt==0 stages
          #pragma unroll
          for (int it = 0; it < 2; ++it)
            gll16((const char*)rb + aoff[it] + ndt * 128,
                  lds + nb * 32768 + ldst[it]);
        }
        #pragma unroll
        for (int it = 0; it < 2; ++it)
          gll16((const char*)cbh + boff[it] + nktoff + ndt * 128,
                lds + nb * 32768 + 16384 + ldst[it]);
      }
      if (dt == 0) {
        #pragma unroll
        for (int i = 0; i < 2; ++i)
          #pragma unroll
          for (int j = 0; j < 4; ++j)
            acc[i][j] = (f4){0.f, 0.f, 0.f, 0.f};
      }
      #pragma unroll
      for (int kk = 0; kk < 2; ++kk) {
        b8 af[2], bb[4];
        if (kt == 0) {                  // load A frags from LDS, cache in regs
          #pragma unroll
          for (int mf = 0; mf < 2; ++mf) {
            af[mf] = *(const b8*)(lds + buf * 32768 + offA[mf][kk]);
            ar[dt][kk][mf] = af[mf];
          }
        } else {                        // reuse cached A frags
          #pragma unroll
          for (int mf = 0; mf < 2; ++mf) af[mf] = ar[dt][kk][mf];
        }
        #pragma unroll
        for (int nf = 0; nf < 4; ++nf)
          bb[nf] = *(const b8*)(lds + buf * 32768 + 16384 + offB[nf][kk]);
        #pragma unroll
        for (int mf = 0; mf < 2; ++mf)
          #pragma unroll
          for (int nf = 0; nf < 4; ++nf)
            acc[mf][nf] = __builtin_amdgcn_mfma_f32_16x16x32_bf16(
                af[mf], bb[nf], acc[mf][nf], 0, 0, 0);
      }
      if (dt == 3) {                    // fold tile kt into running top-2
        float cn[4]; int kg[4];
        #pragma unroll
        for (int nf = 0; nf < 4; ++nf) {
          kg[nf] = kgb + kt * 128 + nf * 16;
          cn[nf] = cchat[kg[nf]];
        }
        #pragma unroll
        for (int mf = 0; mf < 2; ++mf)
          #pragma unroll
          for (int r = 0; r < 4; ++r) {
            const int s0 = mf * 4 + r;
            #pragma unroll
            for (int nf = 0; nf < 4; ++nf) {
              float s = fmaf(-2.f, acc[mf][nf][r], cn[nf]);
              bool  c = s < tv1[s0];
              float m2 = fminf(tv2[s0], s);
              tv2[s0] = c ? tv1[s0] : m2;
              ti1[s0] = c ? kg[nf] : ti1[s0];
              tv1[s0] = c ? s : tv1[s0];
            }
          }
      }
      __syncthreads();                  // drains vmcnt: next buffer ready
    }
  }

  // ---- single end-of-block reduction (alias lds as merge buffer) ----
  float* Mv1 = (float*)lds;             // [128][2]
  int*   Mi1 = (int*)(lds + 1024);
  float* Mv2 = (float*)(lds + 2048);

  #pragma unroll
  for (int s0 = 0; s0 < 8; ++s0) {
    float v1 = tv1[s0], v2 = tv2[s0];
    int   i1 = ti1[s0];
    #pragma unroll
    for (int m = 1; m < 16; m <<= 1) {
      float qv1 = __shfl_xor(v1, m);
      int   qi1 = __shfl_xor(i1, m);
      float qv2 = __shfl_xor(v2, m);
      bool  qw  = (qv1 < v1) || (qv1 == v1 && qi1 < i1);
      float lose = qw ? v1 : qv1;
      float wv2  = qw ? qv2 : v2;
      v2 = fminf(wv2, lose);
      if (qw) { v1 = qv1; i1 = qi1; }
    }
    if ((l & 15) == 0) {
      int mf = s0 >> 2, r = s0 & 3;
      int rowL = mw * 32 + mf * 16 + (l >> 4) * 4 + r;
      Mv1[rowL * 2 + kw] = v1; Mi1[rowL * 2 + kw] = i1; Mv2[rowL * 2 + kw] = v2;
    }
  }
  __syncthreads();
  if (tid < 128) {
    float a1 = Mv1[tid * 2],     a2 = Mv2[tid * 2];     int a1i = Mi1[tid * 2];
    float b1 = Mv1[tid * 2 + 1], b2 = Mv2[tid * 2 + 1]; int b1i = Mi1[tid * 2 + 1];
    bool  bw = (b1 < a1) || (b1 == a1 && b1i < a1i);
    float v1 = bw ? b1 : a1; int i1 = bw ? b1i : a1i;
    float v2 = fminf(bw ? b2 : a2, bw ? a1 : b1);
    int n = m0 + tid;
    pv1[kblk * NVEC + n] = v1;
    pi1[kblk * NVEC + n] = i1;
    pv2[kblk * NVEC + n] = v2;
  }
}

// ---------------------------------------------------------------------------
// merge: global top2 over KBLK partials; provisional idx; flag near-ties.
// ---------------------------------------------------------------------------
__global__ __launch_bounds__(256) void merge_kernel(
    const float* __restrict__ pv1, const int* __restrict__ pi1,
    const float* __restrict__ pv2, const float* __restrict__ vnorm,
    int* __restrict__ idx, int* __restrict__ flist, int* __restrict__ fslot,
    int* __restrict__ fcount) {
  int n = blockIdx.x * 256 + threadIdx.x;
  float v1 = 3.4e38f, v2 = 3.4e38f; int i1 = 0;
  #pragma unroll
  for (int kb = 0; kb < KBLK; ++kb) {
    float b1 = pv1[kb * NVEC + n]; int b1i = pi1[kb * NVEC + n];
    float b2 = pv2[kb * NVEC + n];
    bool  bw = (b1 < v1) || (b1 == v1 && b1i < i1);
    float lose = bw ? v1 : b1;
    float wv2  = bw ? b2 : v2;
    v2 = fminf(wv2, lose);
    if (bw) { v1 = b1; i1 = b1i; }
  }
  idx[n] = i1;
  float thr = KAPPA * sqrtf(fmaxf(v1 + vnorm[n], 0.f)) + 1e-5f;
  int slot = -1;
  if (v2 - v1 < thr) {
    slot = atomicAdd(fcount, 1);
    flist[slot] = n;
  }
  fslot[n] = slot;
}

// ---------------------------------------------------------------------------
// fb_scan_t: exact f32 rescan for flagged vectors, transposed codebook.
// chunk = FV(8) vectors; grid = 256 chunk-slots x FKS = 8192 blocks.
// ---------------------------------------------------------------------------
__global__ __launch_bounds__(256, 4) void fb_scan_t(
    const float* __restrict__ cbT, const float* __restrict__ cc,
    const float* __restrict__ resid, const int* __restrict__ flist,
    const int* __restrict__ fcount,
    float* __restrict__ fpv, int* __restrict__ fpi) {
  __shared__ float vsT[DIM][FV + 4];       // 48B rows, f4-aligned
  __shared__ float mv[FV][4];
  __shared__ int   mi[FV][4];
  const int cnt = min(*fcount, FCAP);
  const int ks = blockIdx.x & (FKS - 1);
  const int t = threadIdx.x;
  const int w = t >> 6, l = t & 63;
  const int k = ks * 256 + t;
  const float cn = cc[k];

  for (int chunk = blockIdx.x >> 5; chunk * FV < cnt; chunk += 256) {
    __syncthreads();
    #pragma unroll
    for (int v = 0; v < FV; ++v) {
      int s = chunk * FV + v;
      int n = flist[s < cnt ? s : chunk * FV];
      vsT[t][v] = resid[(size_t)n * DIM + t];
    }
    __syncthreads();

    float dot[FV];
    #pragma unroll
    for (int v = 0; v < FV; ++v) dot[v] = 0.f;

    #pragma unroll 8
    for (int d = 0; d < DIM; ++d) {
      float cv = cbT[(size_t)d * NCODE + k];
      f4 a0 = *(const f4*)&vsT[d][0];
      f4 a1 = *(const f4*)&vsT[d][4];
      dot[0] = fmaf(cv, a0[0], dot[0]);
      dot[1] = fmaf(cv, a0[1], dot[1]);
      dot[2] = fmaf(cv, a0[2], dot[2]);
      dot[3] = fmaf(cv, a0[3], dot[3]);
      dot[4] = fmaf(cv, a1[0], dot[4]);
      dot[5] = fmaf(cv, a1[1], dot[5]);
      dot[6] = fmaf(cv, a1[2], dot[6]);
      dot[7] = fmaf(cv, a1[3], dot[7]);
    }

    #pragma unroll
    for (int v = 0; v < FV; ++v) {
      float bv = fmaf(-2.f, dot[v], cn);
      int   bi = k;
      #pragma unroll
      for (int m = 1; m < 64; m <<= 1) {
        float qv = __shfl_xor(bv, m);
        int   qi = __shfl_xor(bi, m);
        if (qv < bv || (qv == bv && qi < bi)) { bv = qv; bi = qi; }
      }
      if (l == 0) { mv[v][w] = bv; mi[v][w] = bi; }
    }
    __syncthreads();
    if (t < FV) {
      float bv = mv[t][0]; int bi = mi[t][0];
      #pragma unroll
      for (int ww = 1; ww < 4; ++ww) {
        float qv = mv[t][ww]; int qi = mi[t][ww];
        if (qv < bv || (qv == bv && qi < bi)) { bv = qv; bi = qi; }
      }
      if (chunk * FV + t < cnt) {
        fpv[(size_t)(chunk * FV + t) * FKS + ks] = bv;
        fpi[(size_t)(chunk * FV + t) * FKS + ks] = bi;
      }
    }
  }
}

// ---------------------------------------------------------------------------
// update: final idx (inline fb-merge for flagged); resid -= cb[idx];
// rb = bf16(resid); rsum; code out as float. One wave per vector.
// ---------------------------------------------------------------------------
__global__ __launch_bounds__(256) void update_kernel(
    const float* __restrict__ cb, const int* __restrict__ idx,
    const int* __restrict__ fslot,
    const float* __restrict__ fpv, const int* __restrict__ fpi,
    float* __restrict__ resid, unsigned short* __restrict__ rb,
    float* __restrict__ rsum_out, float* __restrict__ codes_out, int depth) {
  int n    = blockIdx.x * 4 + (threadIdx.x >> 6);
  int lane = threadIdx.x & 63;
  int s    = fslot[n];                   // wave-uniform
  int bi;
  if (s >= 0) {
    float v = 3.4e38f; int ii = 0x7fffffff;
    if (lane < FKS) { v = fpv[(size_t)s * FKS + lane]; ii = fpi[(size_t)s * FKS + lane]; }
    #pragma unroll
    for (int m = 1; m < FKS; m <<= 1) {
      float qv = __shfl_xor(v, m);
      int   qi = __shfl_xor(ii, m);
      if (qv < v || (qv == v && qi < ii)) { v = qv; ii = qi; }
    }
    bi = __shfl(ii, 0, 64);
  } else {
    bi = idx[n];
  }
  float4 q = *(const float4*)&cb[(size_t)bi * DIM + lane * 4];
  float4 r = *(float4*)&resid[(size_t)n * DIM + lane * 4];
  r.x -= q.x; r.y -= q.y; r.z -= q.z; r.w -= q.w;
  *(float4*)&resid[(size_t)n * DIM + lane * 4] = r;
  b4 hv; hv[0] = (short)f2bf(r.x); hv[1] = (short)f2bf(r.y);
  hv[2] = (short)f2bf(r.z); hv[3] = (short)f2bf(r.w);
  *(b4*)&rb[(size_t)n * DIM + lane * 4] = hv;
  float s2 = r.x * r.x + r.y * r.y + r.z * r.z + r.w * r.w;
  #pragma unroll
  for (int off = 32; off > 0; off >>= 1) s2 += __shfl_down(s2, off, 64);
  if (lane == 0) {
    rsum_out[n] = s2;
    codes_out[n * DEPTH + depth] = (float)bi;
  }
}

// ---------------------------------------------------------------------------
// finalize: quants = x - resid (in place); block 0 reduces commitment loss.
// ---------------------------------------------------------------------------
__global__ __launch_bounds__(256) void finalize(const float* __restrict__ x,
                                                float* __restrict__ out,
                                                const float* __restrict__ rsumL) {
  int i = blockIdx.x * blockDim.x + threadIdx.x;
  float4 r  = *(float4*)&out[(size_t)i * 4];
  float4 xv = *(const float4*)&x[(size_t)i * 4];
  float4 o;
  o.x = xv.x - r.x; o.y = xv.y - r.y; o.z = xv.z - r.z; o.w = xv.w - r.w;
  *(float4*)&out[(size_t)i * 4] = o;

  if (blockIdx.x == 0) {
    __shared__ float sm[256];
    float s = 0.f;
    for (int j = threadIdx.x; j < DEPTH * NVEC; j += 256) s += rsumL[j];
    sm[threadIdx.x] = s;
    __syncthreads();
    for (int off = 128; off > 0; off >>= 1) {
      if (threadIdx.x < off) sm[threadIdx.x] += sm[threadIdx.x + off];
      __syncthreads();
    }
    if (threadIdx.x == 0)
      out[NVEC * DIM] = sm[0] / (float)DEPTH / (float)(NVEC * DIM);
  }
}

// ---------------------------------------------------------------------------
extern "C" void kernel_launch(void* const* d_in, const int* in_sizes, int n_in,
                              void* d_out, int out_size, void* d_ws, size_t ws_size,
                              hipStream_t stream) {
  const float* x  = (const float*)d_in[0];
  const float* cb = (const float*)d_in[1];
  float* out = (float*)d_out;
  char*  wsb = (char*)d_ws;

  // ws layout (~20 MB, under the proven 22.3 MB)
  unsigned short* cbh = (unsigned short*)(wsb);                 // 4 MB (per-depth)
  unsigned short* rb  = (unsigned short*)(wsb + 4194304);       // 4 MB
  float* cbT   = (float*)(wsb + 8388608);                       // 8 MB (per-depth)
  float* cc    = (float*)(wsb + 16777216);                      // 128 KB
  float* cchat = (float*)(wsb + 16908288);                      // 128 KB
  float* pv1   = (float*)(wsb + 17039360);                      // 512 KB
  int*   pi1   = (int*)  (wsb + 17563648);                      // 512 KB
  float* pv2   = (float*)(wsb + 18087936);                      // 512 KB
  float* rsum  = (float*)(wsb + 18612224);                      // 160 KB
  int*   idx   = (int*)  (wsb + 18776064);                      // 32 KB
  int*   flist = (int*)  (wsb + 18808832);                      // 32 KB
  int*   fslot = (int*)  (wsb + 18841600);                      // 32 KB
  int*   fcount= (int*)  (wsb + 18874368);                      // 4 KB pad
  float* fpv   = (float*)(wsb + 18878464);                      // 1 MB
  int*   fpi   = (int*)  (wsb + 19927040);                      // 1 MB

  float* resid     = out;                    // quants region doubles as resid
  float* codes_out = out + NVEC * DIM + 1;

  prep_norms<<<(DEPTH * NCODE) / 4, 256, 0, stream>>>(cb, cc, cchat);
  init_kernel<<<NVEC / 4, 256, 0, stream>>>(x, resid, rb, rsum);

  for (int d = 0; d < DEPTH; ++d) {
    const size_t cbo = (size_t)d * NCODE * DIM;
    prep_depth<<<512, 256, 0, stream>>>(cb + cbo, cbh, cbT);
    coarse_kernel<<<(NVEC / 128) * KBLK, 512, 0, stream>>>(
        rb, cbh, cchat + d * NCODE, pv1, pi1, pv2, fcount);
    merge_kernel<<<NVEC / 256, 256, 0, stream>>>(
        pv1, pi1, pv2, rsum + d * NVEC, idx, flist, fslot, fcount);
    fb_scan_t<<<256 * FKS, 256, 0, stream>>>(
        cbT, cc + d * NCODE, resid, flist, fcount, fpv, fpi);
    update_kernel<<<NVEC / 4, 256, 0, stream>>>(
        cb + cbo, idx, fslot, fpv, fpi, resid, rb,
        rsum + (d + 1) * NVEC, codes_out, d);
  }
  finalize<<<(NVEC * DIM / 4) / 256, 256, 0, stream>>>(x, out, rsum + NVEC);
}